// Round 10
// baseline (210.755 us; speedup 1.0000x reference)
//
#include <hip/hip_runtime.h>
#include <hip/hip_bf16.h>
#include <math.h>

#define POST 128
#define NI 129            // T+1
#define NJK 4225          // 65*65
#define NTOT 16512        // 129*128
#define KBLKS 134         // af k-blocks of 32
#define MBLKS 32          // 512/16
#define KSTEPS32 133      // k-steps of 32 actually computed (k<4256; A=0 past 4224)
#define PANEL_CLAMP 2163184u  // 4225*512 - 16 : last safe 16B source in a W1 panel

typedef __attribute__((ext_vector_type(8))) short bf16x8;
typedef __attribute__((ext_vector_type(4))) float f32x4;
typedef __attribute__((ext_vector_type(4))) unsigned int u32x4;

__device__ __forceinline__ unsigned short f2bf(float f){
    unsigned u = __builtin_bit_cast(unsigned, f);
    unsigned r = (u + 0x7FFFu + ((u >> 16) & 1u)) >> 16;   // RNE
    return (unsigned short)r;
}
__device__ __forceinline__ unsigned pack2(float a, float b){
    return (unsigned)f2bf(a) | ((unsigned)f2bf(b) << 16);
}

__device__ __forceinline__ void gload16(const void* g, void* l){
    __builtin_amdgcn_global_load_lds(
        (const __attribute__((address_space(1))) unsigned int*)g,
        (__attribute__((address_space(3))) unsigned int*)l, 16, 0, 0);
}

// ---------------- K1: build VA (bf16) in MFMA A-fragment granule order --------
// granule (kblk, mblk): 64 lanes x 16B; element (l,j): m=mblk*16+(l&15),
// k = kblk*32 + (l>>4)*8 + j. Zero-padded past NJK.
__global__ void build_af(const float* __restrict__ audio,
                         const float* __restrict__ video,
                         uint4* __restrict__ af)
{
    int gid = blockIdx.x * 256 + threadIdx.x;
    if (gid >= KBLKS * MBLKS * 64) return;
    int lane = gid & 63;
    int mblk = (gid >> 6) & 31;
    int kblk = gid >> 11;
    int m  = mblk * 16 + (lane & 15);
    int k0 = kblk * 32 + (lane >> 4) * 8;
    float vals[8];
#pragma unroll
    for (int j = 0; j < 8; ++j){
        int k = k0 + j;
        float p = 0.f;
        if (k < NJK){
            int jj = k / 65;
            int kk = k - jj * 65;
            float a = (kk == 0) ? 1.f : audio[m * 64 + kk - 1];
            float v = (jj == 0) ? 1.f : video[m * 64 + jj - 1];
            p = a * v;
        }
        vals[j] = p;
    }
    uint4 o;
    o.x = pack2(vals[0], vals[1]);
    o.y = pack2(vals[2], vals[3]);
    o.z = pack2(vals[4], vals[5]);
    o.w = pack2(vals[6], vals[7]);
    af[gid] = o;
}

// ---------------- K2: fused Z = VA @ bf16(W1'), all-gload_lds staging ---------
// 128x128 tile, BK=32, grid 516 = 4 mt x 129 nt, 4 waves (2x2 of 64x64).
// A: bf16 granules -> LDS via global_load_lds (linear, 8KB/step).
// B: RAW fp32 W1 slab (contiguous 16KB/step) -> LDS via global_load_lds;
//    fp32->bf16 convert happens at fragment-read time (8 dword reads + 4 pack2).
// No register staging anywhere -> nothing for the compiler to sink.
__global__ __launch_bounds__(256, 3) void fusion_gemm(
    const float* __restrict__ W1,
    const uint4* __restrict__ af,
    float* __restrict__ Z)
{
    __shared__ __align__(16) char lds[49152];
    // buf b at b*24576: [0,8K) A bf16 granules | [8K,24K) B fp32 [k 0..31][n 0..127]

    // bijective XCD swizzle (nwg=516: q=64, r=4)
    int orig = blockIdx.x;
    int xcd  = orig & 7;
    int base = (xcd < 4) ? xcd * 65 : 260 + (xcd - 4) * 64;
    int w    = base + (orig >> 3);
    int nt = w >> 2;          // 0..128
    int mt = w & 3;           // 0..3

    int t    = threadIdx.x;
    int lane = t & 63;
    int wv   = t >> 6;
    int wm   = wv >> 1, wn = wv & 1;

    f32x4 acc[4][4] = {};

    const char* wpanel = (const char*)(W1 + (size_t)nt * (NJK * 128));
    const char* afb    = (const char*)af;

    // staging: 24 chunks of 1KB (8 A + 16 B), 6 per wave, lane*16 within chunk
#define STAGE(ks_, buf_)                                                       \
    do {                                                                       \
        char* dst0_ = lds + (buf_) * 24576;                                    \
        _Pragma("unroll")                                                      \
        for (int i_ = 0; i_ < 6; ++i_){                                        \
            int chunk_ = wv * 6 + i_;                                          \
            if (chunk_ < 8){                                                   \
                const char* src_ = afb + ((size_t)(ks_) * 32 + mt * 8 + chunk_) * 1024 + lane * 16; \
                gload16(src_, dst0_ + chunk_ * 1024);                          \
            } else {                                                           \
                unsigned boff_ = (unsigned)(ks_) * 16384u + (unsigned)(chunk_ - 8) * 1024u + (unsigned)lane * 16u; \
                if (boff_ > PANEL_CLAMP) boff_ = PANEL_CLAMP;  /* tail-safe */ \
                gload16(wpanel + boff_, dst0_ + chunk_ * 1024);                \
            }                                                                  \
        }                                                                      \
    } while (0)

    // prologue
    STAGE(0, 0);
    __syncthreads();

    for (int ks = 0; ks < KSTEPS32; ++ks){
        if (ks + 1 < KSTEPS32)
            STAGE(ks + 1, (ks + 1) & 1);

        // ---- compute from buf ks&1
        const char* sa  = lds + (ks & 1) * 24576;
        const char* sbB = sa + 8192;

        bf16x8 a[4], b[4];
#pragma unroll
        for (int f = 0; f < 4; ++f)
            a[f] = *(const bf16x8*)(sa + (wm * 4 + f) * 1024 + lane * 16);

        int kbase = (lane >> 4) * 8;
#pragma unroll
        for (int g = 0; g < 4; ++g){
            int nbyte = (wn * 64 + g * 16 + (lane & 15)) * 4;
            float vv[8];
#pragma unroll
            for (int j = 0; j < 8; ++j)
                vv[j] = *(const float*)(sbB + (kbase + j) * 512 + nbyte);
            u32x4 ub;
            ub.x = pack2(vv[0], vv[1]);
            ub.y = pack2(vv[2], vv[3]);
            ub.z = pack2(vv[4], vv[5]);
            ub.w = pack2(vv[6], vv[7]);
            b[g] = __builtin_bit_cast(bf16x8, ub);
        }

#pragma unroll
        for (int f = 0; f < 4; ++f)
#pragma unroll
            for (int g = 0; g < 4; ++g)
                acc[f][g] = __builtin_amdgcn_mfma_f32_16x16x32_bf16(a[f], b[g], acc[f][g], 0, 0, 0);

        __syncthreads();
    }

    // epilogue: D layout col=lane&15, row=(lane>>4)*4+reg
    int row0 = mt * 128 + wm * 64 + (lane >> 4) * 4;
    int col0 = nt * 128 + wn * 64 + (lane & 15);
#pragma unroll
    for (int f = 0; f < 4; ++f)
#pragma unroll
        for (int g = 0; g < 4; ++g)
#pragma unroll
            for (int r = 0; r < 4; ++r)
                Z[(size_t)(row0 + f * 16 + r) * NTOT + col0 + g * 16] = acc[f][g][r];
}

// ---------------- K3: y1 = relu(b1 + sum_i t1_i * Z[:,i,:]); y2; sigmoid head --
__global__ void tail_mlp(const float* __restrict__ Z,
                         const float* __restrict__ text,
                         const float* __restrict__ b1,
                         const float* __restrict__ W2,
                         const float* __restrict__ b2,
                         const float* __restrict__ W3,
                         const float* __restrict__ b3,
                         float* __restrict__ out)
{
    int b   = blockIdx.x;     // 512
    int tid = threadIdx.x;    // 128
    __shared__ float t1s[NI];
    __shared__ float y1s[POST];
    __shared__ float red[2];

    t1s[tid + 1] = text[b * 128 + tid];
    if (tid == 0) t1s[0] = 1.f;
    __syncthreads();

    const float* zrow = Z + (size_t)b * NTOT;
    float acc = 0.f;
    for (int i = 0; i < NI; ++i)
        acc = fmaf(t1s[i], zrow[i * 128 + tid], acc);
    acc += b1[tid];
    float y1 = fmaxf(acc, 0.f);
    y1s[tid] = y1;
    __syncthreads();

    float a2 = b2[tid];
    for (int q = 0; q < 128; ++q)
        a2 = fmaf(y1s[q], W2[q * 128 + tid], a2);
    float y2 = fmaxf(a2, 0.f);

    float part = y2 * W3[tid];
#pragma unroll
    for (int off = 32; off > 0; off >>= 1)
        part += __shfl_down(part, off);
    if ((tid & 63) == 0) red[tid >> 6] = part;
    __syncthreads();
    if (tid == 0){
        float z = red[0] + red[1] + b3[0];
        out[b] = 6.f / (1.f + expf(-z)) - 3.f;
    }
}

extern "C" void kernel_launch(void* const* d_in, const int* in_sizes, int n_in,
                              void* d_out, int out_size, void* d_ws, size_t ws_size,
                              hipStream_t stream)
{
    const float* audio = (const float*)d_in[0];
    const float* video = (const float*)d_in[1];
    const float* text  = (const float*)d_in[2];
    const float* W1    = (const float*)d_in[3];
    const float* b1    = (const float*)d_in[4];
    const float* W2    = (const float*)d_in[5];
    const float* b2    = (const float*)d_in[6];
    const float* W3    = (const float*)d_in[7];
    const float* b3    = (const float*)d_in[8];
    float* out = (float*)d_out;

    char* ws = (char*)d_ws;
    uint4* af = (uint4*)ws;                       // 4,390,912 B
    float* Z  = (float*)(ws + (8u << 20));        // 33,816,576 B

    int af_granules = KBLKS * MBLKS * 64;         // 274432 threads
    build_af<<<(af_granules + 255) / 256, 256, 0, stream>>>(audio, video, af);
    fusion_gemm<<<516, 256, 0, stream>>>(W1, af, Z);
    tail_mlp<<<512, 128, 0, stream>>>(Z, text, b1, W2, b2, W3, b3, out);
}